// Round 4
// baseline (295.401 us; speedup 1.0000x reference)
//
#include <hip/hip_runtime.h>

// GraphUpsamplingBlock via bf16 MFMA, transposed chain:
//   H^T = relu(W1^T @ X^T); E^T = relu((0.25*W2^T) @ H^T); out^T = relu(W3^T @ E^T)
// Per wave = one quadrant, 32 coarse nodes (one block = 32 nodes x 4 quadrants).
// All inter-stage activations stored in B-fragment lane order so every read is
// one contiguous ds_read_b128; bf16 packing via v_cvt_pk_bf16_f32.

typedef __attribute__((ext_vector_type(8))) short bf16x8;
typedef __attribute__((ext_vector_type(4))) float f32x4;
typedef __attribute__((ext_vector_type(4))) unsigned int u32x4;

#define WCOARSE 224
#define WFINE   448
#define NCOARSE 55552

__device__ __forceinline__ unsigned int f2bf(float f) {
    unsigned int u = __builtin_bit_cast(unsigned int, f);
    return (u + 0x7FFFu + ((u >> 16) & 1u)) >> 16;  // RNE
}

__device__ __forceinline__ unsigned int cvtpk(float lo, float hi) {
    unsigned int r;
    asm("v_cvt_pk_bf16_f32 %0, %1, %2" : "=v"(r) : "v"(lo), "v"(hi));
    return r;
}

// ws layout (uint16): A1[4][16][64][8] | A2[4][8][64][8] | A3[4][32][64][8]  (224 KB)
__global__ void build_frags(const float* __restrict__ W_emb,
                            const float* __restrict__ W_edge,
                            const float* __restrict__ W_node,
                            unsigned short* __restrict__ ws) {
    int i = blockIdx.x * 256 + threadIdx.x;  // 448*256 = 114688 exact
    float val;
    if (i < 32768) {                       // A1 = W_emb[q]^T  (hf x k)
        int v = i & 7, lane = (i >> 3) & 63, frag = (i >> 9) & 15, q = i >> 13;
        int ri = frag >> 2, kt = frag & 3;
        int hf = ri * 16 + (lane & 15);
        int k  = kt * 32 + (lane >> 4) * 8 + v;
        val = W_emb[(q * 128 + k) * 64 + hf];
    } else if (i < 49152) {                // A2 = 0.25 * W_edge[q][2:66]^T (ef x hf)
        int j = i - 32768;
        int v = j & 7, lane = (j >> 3) & 63, frag = (j >> 9) & 7, q = j >> 12;
        int ri = frag >> 1, kt = frag & 1;
        int ef = ri * 16 + (lane & 15);
        int hf = kt * 32 + (lane >> 4) * 8 + v;
        val = 0.25f * W_edge[(q * 130 + 2 + hf) * 64 + ef];
    } else {                               // A3 = W_node[128+64q : 192+64q]^T (f x ef)
        int j = i - 49152;
        int v = j & 7, lane = (j >> 3) & 63, frag = (j >> 9) & 31, q = j >> 14;
        int tt = frag >> 1, kt = frag & 1;
        int f  = tt * 16 + (lane & 15);
        int ef = kt * 32 + (lane >> 4) * 8 + v;
        val = W_node[(128 + 64 * q + ef) * 256 + f];
    }
    ws[i] = (unsigned short)f2bf(val);
}

__global__ __launch_bounds__(256, 3) void upsample_mfma(
    const float* __restrict__ x,
    const unsigned short* __restrict__ wsf,
    float* __restrict__ out) {

    __shared__ unsigned int Xb[2048];      // 8 KB: ((nj*4+kt)*64+lane)*4+w  (shared by 4 waves)
    __shared__ unsigned int HEb[4][1024];  // 4 KB/wave: ((nj*2+kt)*64+lane)*4+w  (H then E)

    const int t    = threadIdx.x;
    const int wave = t >> 6;
    const int lane = t & 63;
    const int c    = lane & 15;
    const int g    = lane >> 4;
    const int q    = wave;
    const int p0   = blockIdx.x * 32;   // 55552 = 1736*32, and 224%32==0 -> tile stays in one coarse row

    // ---- Phase 0: cooperative x -> bf16 B1 fragments (once per block) ----
#pragma unroll
    for (int half = 0; half < 2; ++half) {
        const int u  = t * 8 + half * 4;          // 4 consecutive u32
        const int g4 = u >> 2;                    // fragment-quarter index 0..511
        const int ln = g4 & 63;
        const int kt = (g4 >> 6) & 3;
        const int nj = g4 >> 8;
        const int node = nj * 16 + (ln & 15);
        const int kb   = kt * 32 + (ln >> 4) * 8;
        const float* src = x + (size_t)(p0 + node) * 128 + kb;
        const float4 a = *reinterpret_cast<const float4*>(src);
        const float4 b = *reinterpret_cast<const float4*>(src + 4);
        u32x4 w = { cvtpk(a.x, a.y), cvtpk(a.z, a.w), cvtpk(b.x, b.y), cvtpk(b.z, b.w) };
        *reinterpret_cast<u32x4*>(&Xb[u]) = w;
    }
    __syncthreads();

    const unsigned short* A1 = wsf + q * (16 * 512);
    const unsigned short* A2 = wsf + 32768 + q * (8 * 512);
    const unsigned short* A3 = wsf + 49152 + q * (32 * 512);
    unsigned int* HE = HEb[wave];

    // ---- Stage 1: C1 = H^T = W1^T @ X^T,  K=128 ----
    bf16x8 B1[2][4];
#pragma unroll
    for (int nj = 0; nj < 2; ++nj)
#pragma unroll
        for (int kt = 0; kt < 4; ++kt)
            B1[nj][kt] = *reinterpret_cast<const bf16x8*>(&Xb[((nj * 4 + kt) * 64 + lane) * 4]);

    f32x4 c1[4][2] = {};
#pragma unroll
    for (int kt = 0; kt < 4; ++kt)
#pragma unroll
        for (int ri = 0; ri < 4; ++ri) {
            bf16x8 a = *reinterpret_cast<const bf16x8*>(A1 + ((ri * 4 + kt) * 64 + lane) * 8);
#pragma unroll
            for (int nj = 0; nj < 2; ++nj)
                c1[ri][nj] = __builtin_amdgcn_mfma_f32_16x16x32_bf16(a, B1[nj][kt], c1[ri][nj], 0, 0, 0);
        }
    // relu + pack + write H in B-fragment lane order:
    // feat f of node nj*16+c -> u32 ((nj*2+(f>>5))*64 + ((f>>3)&3)*16 + c)*4 + ((f&7)>>1)
#pragma unroll
    for (int ri = 0; ri < 4; ++ri)
#pragma unroll
        for (int nj = 0; nj < 2; ++nj) {
            f32x4 v = c1[ri][nj];
            uint2 w;
            w.x = cvtpk(fmaxf(v[0], 0.f), fmaxf(v[1], 0.f));
            w.y = cvtpk(fmaxf(v[2], 0.f), fmaxf(v[3], 0.f));
            const int gt = (2 * ri + (g >> 1)) & 3;
            *reinterpret_cast<uint2*>(&HE[((nj * 2 + (ri >> 1)) * 64 + gt * 16 + c) * 4 + (g & 1) * 2]) = w;
        }

    // ---- Stage 2: C2 = E^T = (0.25*W2^T) @ H^T,  K=64 ----
    bf16x8 B2[2][2];
#pragma unroll
    for (int nj = 0; nj < 2; ++nj)
#pragma unroll
        for (int kt = 0; kt < 2; ++kt)
            B2[nj][kt] = *reinterpret_cast<const bf16x8*>(&HE[((nj * 2 + kt) * 64 + lane) * 4]);

    f32x4 c2[4][2] = {};
#pragma unroll
    for (int kt = 0; kt < 2; ++kt)
#pragma unroll
        for (int ri = 0; ri < 4; ++ri) {
            bf16x8 a = *reinterpret_cast<const bf16x8*>(A2 + ((ri * 2 + kt) * 64 + lane) * 8);
#pragma unroll
            for (int nj = 0; nj < 2; ++nj)
                c2[ri][nj] = __builtin_amdgcn_mfma_f32_16x16x32_bf16(a, B2[nj][kt], c2[ri][nj], 0, 0, 0);
        }
    // relu + pack + write E (same layout; aliases H buffer, same-wave DS order is safe)
#pragma unroll
    for (int ri = 0; ri < 4; ++ri)
#pragma unroll
        for (int nj = 0; nj < 2; ++nj) {
            f32x4 v = c2[ri][nj];
            uint2 w;
            w.x = cvtpk(fmaxf(v[0], 0.f), fmaxf(v[1], 0.f));
            w.y = cvtpk(fmaxf(v[2], 0.f), fmaxf(v[3], 0.f));
            const int gt = (2 * ri + (g >> 1)) & 3;
            *reinterpret_cast<uint2*>(&HE[((nj * 2 + (ri >> 1)) * 64 + gt * 16 + c) * 4 + (g & 1) * 2]) = w;
        }

    // ---- Stage 3: out^T = W3^T @ E^T,  K=64, 256 features, scatter store ----
    bf16x8 B3[2][2];
#pragma unroll
    for (int nj = 0; nj < 2; ++nj)
#pragma unroll
        for (int kt = 0; kt < 2; ++kt)
            B3[nj][kt] = *reinterpret_cast<const bf16x8*>(&HE[((nj * 2 + kt) * 64 + lane) * 4]);

    const int dr  = (q == 1 || q == 2) ? 1 : 0;
    const int dc  = (q == 0 || q == 1) ? 1 : 0;
    const int pr  = p0 / WCOARSE;            // tile never crosses a coarse row
    const int pc0 = p0 - pr * WCOARSE;
    int fb[2];
#pragma unroll
    for (int nj = 0; nj < 2; ++nj)
        fb[nj] = ((2 * pr + dr) * WFINE + 2 * (pc0 + nj * 16 + c) + dc) * 256;

#pragma unroll 4
    for (int tt = 0; tt < 16; ++tt) {
        bf16x8 a0 = *reinterpret_cast<const bf16x8*>(A3 + ((tt * 2 + 0) * 64 + lane) * 8);
        bf16x8 a1 = *reinterpret_cast<const bf16x8*>(A3 + ((tt * 2 + 1) * 64 + lane) * 8);
#pragma unroll
        for (int nj = 0; nj < 2; ++nj) {
            f32x4 o = {};
            o = __builtin_amdgcn_mfma_f32_16x16x32_bf16(a0, B3[nj][0], o, 0, 0, 0);
            o = __builtin_amdgcn_mfma_f32_16x16x32_bf16(a1, B3[nj][1], o, 0, 0, 0);
            f32x4 s;
            s[0] = fmaxf(o[0], 0.f);
            s[1] = fmaxf(o[1], 0.f);
            s[2] = fmaxf(o[2], 0.f);
            s[3] = fmaxf(o[3], 0.f);
            __builtin_nontemporal_store(s, reinterpret_cast<f32x4*>(out + fb[nj] + tt * 16 + g * 4));
        }
    }
}

extern "C" void kernel_launch(void* const* d_in, const int* in_sizes, int n_in,
                              void* d_out, int out_size, void* d_ws, size_t ws_size,
                              hipStream_t stream) {
    const float* x      = (const float*)d_in[0];
    const float* W_emb  = (const float*)d_in[1];
    const float* W_edge = (const float*)d_in[2];
    const float* W_node = (const float*)d_in[3];
    unsigned short* ws  = (unsigned short*)d_ws;   // 224 KB of weight fragments
    float* out          = (float*)d_out;

    build_frags<<<448, 256, 0, stream>>>(W_emb, W_edge, W_node, ws);
    upsample_mfma<<<1736, 256, 0, stream>>>(x, ws, out);
}

// Round 5
// 268.926 us; speedup vs baseline: 1.0984x; 1.0984x over previous
//
#include <hip/hip_runtime.h>

// GraphUpsamplingBlock via bf16 MFMA, transposed chain:
//   H^T = relu(W1^T @ X^T); E^T = relu((0.25*W2^T) @ H^T); out^T = relu(W3^T @ E^T)
// Per wave = one quadrant, 32 coarse nodes (one block = 32 nodes x 4 quadrants).
// All inter-stage activations stored in B-fragment lane order so every read is
// one contiguous ds_read_b128; bf16 packing via v_cvt_pk_bf16_f32.
// Stores are plain (L2-cached): the 64B-segment scatter relies on L2
// write-combining across the tt loop — nontemporal stores regressed 30+ us.

typedef __attribute__((ext_vector_type(8))) short bf16x8;
typedef __attribute__((ext_vector_type(4))) float f32x4;
typedef __attribute__((ext_vector_type(4))) unsigned int u32x4;

#define WCOARSE 224
#define WFINE   448
#define NCOARSE 55552

__device__ __forceinline__ unsigned int f2bf(float f) {
    unsigned int u = __builtin_bit_cast(unsigned int, f);
    return (u + 0x7FFFu + ((u >> 16) & 1u)) >> 16;  // RNE
}

__device__ __forceinline__ unsigned int cvtpk(float lo, float hi) {
    unsigned int r;
    asm("v_cvt_pk_bf16_f32 %0, %1, %2" : "=v"(r) : "v"(lo), "v"(hi));
    return r;
}

// ws layout (uint16): A1[4][16][64][8] | A2[4][8][64][8] | A3[4][32][64][8]  (224 KB)
__global__ void build_frags(const float* __restrict__ W_emb,
                            const float* __restrict__ W_edge,
                            const float* __restrict__ W_node,
                            unsigned short* __restrict__ ws) {
    int i = blockIdx.x * 256 + threadIdx.x;  // 448*256 = 114688 exact
    float val;
    if (i < 32768) {                       // A1 = W_emb[q]^T  (hf x k)
        int v = i & 7, lane = (i >> 3) & 63, frag = (i >> 9) & 15, q = i >> 13;
        int ri = frag >> 2, kt = frag & 3;
        int hf = ri * 16 + (lane & 15);
        int k  = kt * 32 + (lane >> 4) * 8 + v;
        val = W_emb[(q * 128 + k) * 64 + hf];
    } else if (i < 49152) {                // A2 = 0.25 * W_edge[q][2:66]^T (ef x hf)
        int j = i - 32768;
        int v = j & 7, lane = (j >> 3) & 63, frag = (j >> 9) & 7, q = j >> 12;
        int ri = frag >> 1, kt = frag & 1;
        int ef = ri * 16 + (lane & 15);
        int hf = kt * 32 + (lane >> 4) * 8 + v;
        val = 0.25f * W_edge[(q * 130 + 2 + hf) * 64 + ef];
    } else {                               // A3 = W_node[128+64q : 192+64q]^T (f x ef)
        int j = i - 49152;
        int v = j & 7, lane = (j >> 3) & 63, frag = (j >> 9) & 31, q = j >> 14;
        int tt = frag >> 1, kt = frag & 1;
        int f  = tt * 16 + (lane & 15);
        int ef = kt * 32 + (lane >> 4) * 8 + v;
        val = W_node[(128 + 64 * q + ef) * 256 + f];
    }
    ws[i] = (unsigned short)f2bf(val);
}

__global__ __launch_bounds__(256, 3) void upsample_mfma(
    const float* __restrict__ x,
    const unsigned short* __restrict__ wsf,
    float* __restrict__ out) {

    __shared__ unsigned int Xb[2048];      // 8 KB: ((nj*4+kt)*64+lane)*4+w  (shared by 4 waves)
    __shared__ unsigned int HEb[4][1024];  // 4 KB/wave: ((nj*2+kt)*64+lane)*4+w  (H then E)

    const int t    = threadIdx.x;
    const int wave = t >> 6;
    const int lane = t & 63;
    const int c    = lane & 15;
    const int g    = lane >> 4;
    const int q    = wave;
    const int p0   = blockIdx.x * 32;   // 55552 = 1736*32, and 224%32==0 -> tile stays in one coarse row

    // ---- Phase 0: cooperative x -> bf16 B1 fragments (once per block) ----
#pragma unroll
    for (int half = 0; half < 2; ++half) {
        const int u  = t * 8 + half * 4;          // 4 consecutive u32
        const int g4 = u >> 2;                    // fragment-quarter index 0..511
        const int ln = g4 & 63;
        const int kt = (g4 >> 6) & 3;
        const int nj = g4 >> 8;
        const int node = nj * 16 + (ln & 15);
        const int kb   = kt * 32 + (ln >> 4) * 8;
        const float* src = x + (size_t)(p0 + node) * 128 + kb;
        const float4 a = *reinterpret_cast<const float4*>(src);
        const float4 b = *reinterpret_cast<const float4*>(src + 4);
        u32x4 w = { cvtpk(a.x, a.y), cvtpk(a.z, a.w), cvtpk(b.x, b.y), cvtpk(b.z, b.w) };
        *reinterpret_cast<u32x4*>(&Xb[u]) = w;
    }
    __syncthreads();

    const unsigned short* A1 = wsf + q * (16 * 512);
    const unsigned short* A2 = wsf + 32768 + q * (8 * 512);
    const unsigned short* A3 = wsf + 49152 + q * (32 * 512);
    unsigned int* HE = HEb[wave];

    // ---- Stage 1: C1 = H^T = W1^T @ X^T,  K=128 ----
    bf16x8 B1[2][4];
#pragma unroll
    for (int nj = 0; nj < 2; ++nj)
#pragma unroll
        for (int kt = 0; kt < 4; ++kt)
            B1[nj][kt] = *reinterpret_cast<const bf16x8*>(&Xb[((nj * 4 + kt) * 64 + lane) * 4]);

    f32x4 c1[4][2] = {};
#pragma unroll
    for (int kt = 0; kt < 4; ++kt)
#pragma unroll
        for (int ri = 0; ri < 4; ++ri) {
            bf16x8 a = *reinterpret_cast<const bf16x8*>(A1 + ((ri * 4 + kt) * 64 + lane) * 8);
#pragma unroll
            for (int nj = 0; nj < 2; ++nj)
                c1[ri][nj] = __builtin_amdgcn_mfma_f32_16x16x32_bf16(a, B1[nj][kt], c1[ri][nj], 0, 0, 0);
        }
    // relu + pack + write H in B-fragment lane order:
    // feat f of node nj*16+c -> u32 ((nj*2+(f>>5))*64 + ((f>>3)&3)*16 + c)*4 + ((f&7)>>1)
#pragma unroll
    for (int ri = 0; ri < 4; ++ri)
#pragma unroll
        for (int nj = 0; nj < 2; ++nj) {
            f32x4 v = c1[ri][nj];
            uint2 w;
            w.x = cvtpk(fmaxf(v[0], 0.f), fmaxf(v[1], 0.f));
            w.y = cvtpk(fmaxf(v[2], 0.f), fmaxf(v[3], 0.f));
            const int gt = (2 * ri + (g >> 1)) & 3;
            *reinterpret_cast<uint2*>(&HE[((nj * 2 + (ri >> 1)) * 64 + gt * 16 + c) * 4 + (g & 1) * 2]) = w;
        }

    // ---- Stage 2: C2 = E^T = (0.25*W2^T) @ H^T,  K=64 ----
    bf16x8 B2[2][2];
#pragma unroll
    for (int nj = 0; nj < 2; ++nj)
#pragma unroll
        for (int kt = 0; kt < 2; ++kt)
            B2[nj][kt] = *reinterpret_cast<const bf16x8*>(&HE[((nj * 2 + kt) * 64 + lane) * 4]);

    f32x4 c2[4][2] = {};
#pragma unroll
    for (int kt = 0; kt < 2; ++kt)
#pragma unroll
        for (int ri = 0; ri < 4; ++ri) {
            bf16x8 a = *reinterpret_cast<const bf16x8*>(A2 + ((ri * 2 + kt) * 64 + lane) * 8);
#pragma unroll
            for (int nj = 0; nj < 2; ++nj)
                c2[ri][nj] = __builtin_amdgcn_mfma_f32_16x16x32_bf16(a, B2[nj][kt], c2[ri][nj], 0, 0, 0);
        }
    // relu + pack + write E (same layout; aliases H buffer, same-wave DS order is safe)
#pragma unroll
    for (int ri = 0; ri < 4; ++ri)
#pragma unroll
        for (int nj = 0; nj < 2; ++nj) {
            f32x4 v = c2[ri][nj];
            uint2 w;
            w.x = cvtpk(fmaxf(v[0], 0.f), fmaxf(v[1], 0.f));
            w.y = cvtpk(fmaxf(v[2], 0.f), fmaxf(v[3], 0.f));
            const int gt = (2 * ri + (g >> 1)) & 3;
            *reinterpret_cast<uint2*>(&HE[((nj * 2 + (ri >> 1)) * 64 + gt * 16 + c) * 4 + (g & 1) * 2]) = w;
        }

    // ---- Stage 3: out^T = W3^T @ E^T,  K=64, 256 features, scatter store ----
    bf16x8 B3[2][2];
#pragma unroll
    for (int nj = 0; nj < 2; ++nj)
#pragma unroll
        for (int kt = 0; kt < 2; ++kt)
            B3[nj][kt] = *reinterpret_cast<const bf16x8*>(&HE[((nj * 2 + kt) * 64 + lane) * 4]);

    const int dr  = (q == 1 || q == 2) ? 1 : 0;
    const int dc  = (q == 0 || q == 1) ? 1 : 0;
    const int pr  = p0 / WCOARSE;            // tile never crosses a coarse row
    const int pc0 = p0 - pr * WCOARSE;
    int fb[2];
#pragma unroll
    for (int nj = 0; nj < 2; ++nj)
        fb[nj] = ((2 * pr + dr) * WFINE + 2 * (pc0 + nj * 16 + c) + dc) * 256;

#pragma unroll 4
    for (int tt = 0; tt < 16; ++tt) {
        bf16x8 a0 = *reinterpret_cast<const bf16x8*>(A3 + ((tt * 2 + 0) * 64 + lane) * 8);
        bf16x8 a1 = *reinterpret_cast<const bf16x8*>(A3 + ((tt * 2 + 1) * 64 + lane) * 8);
#pragma unroll
        for (int nj = 0; nj < 2; ++nj) {
            f32x4 o = {};
            o = __builtin_amdgcn_mfma_f32_16x16x32_bf16(a0, B3[nj][0], o, 0, 0, 0);
            o = __builtin_amdgcn_mfma_f32_16x16x32_bf16(a1, B3[nj][1], o, 0, 0, 0);
            f32x4 s;
            s[0] = fmaxf(o[0], 0.f);
            s[1] = fmaxf(o[1], 0.f);
            s[2] = fmaxf(o[2], 0.f);
            s[3] = fmaxf(o[3], 0.f);
            *reinterpret_cast<f32x4*>(out + fb[nj] + tt * 16 + g * 4) = s;
        }
    }
}

extern "C" void kernel_launch(void* const* d_in, const int* in_sizes, int n_in,
                              void* d_out, int out_size, void* d_ws, size_t ws_size,
                              hipStream_t stream) {
    const float* x      = (const float*)d_in[0];
    const float* W_emb  = (const float*)d_in[1];
    const float* W_edge = (const float*)d_in[2];
    const float* W_node = (const float*)d_in[3];
    unsigned short* ws  = (unsigned short*)d_ws;   // 224 KB of weight fragments
    float* out          = (float*)d_out;

    build_frags<<<448, 256, 0, stream>>>(W_emb, W_edge, W_node, ws);
    upsample_mfma<<<1736, 256, 0, stream>>>(x, ws, out);
}